// Round 5
// baseline (106.993 us; speedup 1.0000x reference)
//
#include <hip/hip_runtime.h>
#include <stdint.h>

// Problem constants
#define D_DIM 512
#define B_ROWS 4096
#define N_ROWS 8192
// (1/TEMPERATURE) * log2(e) : exp(x/T) == exp2(x * SCALE_L2E)
#define SCALE_L2E 14.426950408889634f

#define BM 256                      // square tile edge
#define NHC 16                      // half-chunks of K=32
#define NT (N_ROWS / BM)            // 32 tile rows/cols
#define NPAIRS (NT * (NT + 1) / 2)  // 528, divisible by 8

typedef __attribute__((ext_vector_type(8))) __bf16 bf16x8;
typedef __attribute__((ext_vector_type(4))) float f32x4;

using gas1_t = const __attribute__((address_space(1))) void;
using las3_t = __attribute__((address_space(3))) void;
#define GLOAD16(g, l) __builtin_amdgcn_global_load_lds((gas1_t*)(g), (las3_t*)(l), 16, 0, 0)

// round-to-nearest-even float -> bf16 bits
__device__ __forceinline__ unsigned int f2bf(float f) {
    union { float f; unsigned int u; } v; v.f = f;
    unsigned int u = v.u;
    return (u + 0x7FFFu + ((u >> 16) & 1u)) >> 16;
}

// ---------------- K1: normalize rows -> bf16 Zn (half-chunk-tiled), write positive logits --
// Zn layout: [hc=0..15][row=0..8191][32 bf16]  (plane = 512 KiB) so the GEMM stages
// fully-contiguous 8 KiB per gload_lds instruction.
__global__ __launch_bounds__(256) void k_normalize(const float* __restrict__ zi,
                                                   const float* __restrict__ zj,
                                                   unsigned short* __restrict__ Zn,
                                                   float* __restrict__ pos) {
    const int t = threadIdx.x;
    const int lane = t & 63;
    const int i = blockIdx.x * 4 + (t >> 6);
    const float* pa = zi + (size_t)i * D_DIM + lane * 8;
    const float* pb = zj + (size_t)i * D_DIM + lane * 8;
    const float4 a0 = *(const float4*)pa;
    const float4 a1 = *(const float4*)(pa + 4);
    const float4 b0 = *(const float4*)pb;
    const float4 b1 = *(const float4*)(pb + 4);
    float ssi = a0.x*a0.x + a0.y*a0.y + a0.z*a0.z + a0.w*a0.w
              + a1.x*a1.x + a1.y*a1.y + a1.z*a1.z + a1.w*a1.w;
    float ssj = b0.x*b0.x + b0.y*b0.y + b0.z*b0.z + b0.w*b0.w
              + b1.x*b1.x + b1.y*b1.y + b1.z*b1.z + b1.w*b1.w;
    float dt  = a0.x*b0.x + a0.y*b0.y + a0.z*b0.z + a0.w*b0.w
              + a1.x*b1.x + a1.y*b1.y + a1.z*b1.z + a1.w*b1.w;
    #pragma unroll
    for (int off = 1; off < 64; off <<= 1) {
        ssi += __shfl_xor(ssi, off);
        ssj += __shfl_xor(ssj, off);
        dt  += __shfl_xor(dt,  off);
    }
    const float si = 1.0f / fmaxf(sqrtf(ssi), 1e-12f);
    const float sj = 1.0f / fmaxf(sqrtf(ssj), 1e-12f);
    uint4 pi, pj;
    pi.x = f2bf(a0.x * si) | (f2bf(a0.y * si) << 16);
    pi.y = f2bf(a0.z * si) | (f2bf(a0.w * si) << 16);
    pi.z = f2bf(a1.x * si) | (f2bf(a1.y * si) << 16);
    pi.w = f2bf(a1.z * si) | (f2bf(a1.w * si) << 16);
    pj.x = f2bf(b0.x * sj) | (f2bf(b0.y * sj) << 16);
    pj.y = f2bf(b0.z * sj) | (f2bf(b0.w * sj) << 16);
    pj.z = f2bf(b1.x * sj) | (f2bf(b1.y * sj) << 16);
    pj.w = f2bf(b1.z * sj) | (f2bf(b1.w * sj) << 16);
    // lane covers cols lane*8..lane*8+7 -> hc = lane>>2, 16B-seg = lane&3
    const size_t plane = (size_t)N_ROWS * 32;  // elems per hc-plane
    const size_t off0  = (size_t)(lane >> 2) * plane + (lane & 3) * 8;
    *(uint4*)(Zn + off0 + (size_t)i * 32) = pi;
    *(uint4*)(Zn + off0 + (size_t)(B_ROWS + i) * 32) = pj;
    if (lane == 0) pos[i] = 20.0f * dt * si * sj;  // positive logit counted twice: 2*dot/T
}

// ---------------- K2: symmetric fused S = Zn·Zn^T + per-row sum(exp(S/T)) -----------------
// 256x256 tile pair (I<=J) per block; 512 threads = 8 waves (2M x 4N), wave tile 128x64.
// Counted-vmcnt ring pipeline over 16 half-chunks (K=32 each): 4 LDS slots of 32 KiB
// (A 16 KiB + B 16 KiB). Per step: vmcnt(8) [2 future slots stay in flight] -> barrier ->
// stage L(hc+3) -> 12 x ds_read_b128 -> lgkmcnt(0)+sched_barrier -> setprio+32 MFMA.
// Ring safety: slot (hc+3)&3 was read in step hc-1, done before this step's barrier;
// vmcnt(8)+barrier makes all waves' L(hc) LDS-visible (per-thread FIFO, 4 loads/slot).
// LDS swizzle: 64B rows, granule = lhi ^ (row&3); staging source pre-permuted to match.
__global__ __launch_bounds__(512, 2) void k_gemm_lse(const unsigned short* __restrict__ Zn,
                                                     float* __restrict__ rowsum_g) {
    __shared__ __align__(16) char lds[4 * 32768];  // 128 KiB: 4 ring slots
    const int t    = threadIdx.x;
    const int lane = t & 63;
    const int w    = t >> 6;
    const int wm   = w >> 2, wn = w & 3;          // 2 x 4 wave grid
    const int l15  = lane & 15, lhi = lane >> 4;

    // XCD-aware swizzle (bijective: NPAIRS % 8 == 0), then triangular decode
    int bid = (blockIdx.x & 7) * (NPAIRS / 8) + (blockIdx.x >> 3);
    int I = 0;
    while (bid >= NT - I) { bid -= NT - I; ++I; }
    const int J = I + bid;
    const int rowB = I * BM, colB = J * BM;
    const bool dg = (I == J);

    const char* Zb = (const char*)Zn;
    const size_t PLANE = (size_t)N_ROWS * 64;  // bytes per hc-plane

    // staging: instr q covers tile rows q*128 + (t>>2); 16B-granule (t&3).
    // granule (r, s') holds global K-seg s' ^ (r&3)  [inverse of the read swizzle]
    auto stage = [&](int slotIdx, int hc) {
        char* sb = (char*)lds + slotIdx * 32768;
        const char* gA = Zb + (size_t)hc * PLANE + (size_t)rowB * 64;
        const char* gB = Zb + (size_t)hc * PLANE + (size_t)colB * 64;
        #pragma unroll
        for (int q = 0; q < 2; ++q) {
            const int r  = q * 128 + (t >> 2);
            const int sp = (t & 3) ^ (r & 3);
            GLOAD16(gA + r * 64 + sp * 16, sb + q * 8192 + t * 16);
        }
        #pragma unroll
        for (int q = 0; q < 2; ++q) {
            const int r  = q * 128 + (t >> 2);
            const int sp = (t & 3) ^ (r & 3);
            GLOAD16(gB + r * 64 + sp * 16, sb + 16384 + q * 8192 + t * 16);
        }
    };

    f32x4 acc[8][4];
    #pragma unroll
    for (int a = 0; a < 8; ++a)
        #pragma unroll
        for (int b = 0; b < 4; ++b)
            #pragma unroll
            for (int q = 0; q < 4; ++q) acc[a][b][q] = 0.0f;

    // prologue: 3 slots in flight
    stage(0, 0);
    stage(1, 1);
    stage(2, 2);

    #pragma unroll
    for (int hc = 0; hc < NHC; ++hc) {
        if (hc <= 13)      asm volatile("s_waitcnt vmcnt(8)" ::: "memory");
        else if (hc == 14) asm volatile("s_waitcnt vmcnt(4)" ::: "memory");
        else               asm volatile("s_waitcnt vmcnt(0)" ::: "memory");
        __builtin_amdgcn_sched_barrier(0);
        __builtin_amdgcn_s_barrier();
        __builtin_amdgcn_sched_barrier(0);
        if (hc + 3 < NHC) stage((hc + 3) & 3, hc + 3);

        const char* sb = (const char*)lds + (hc & 3) * 32768;
        bf16x8 af[8], bg[4];
        #pragma unroll
        for (int mi = 0; mi < 8; ++mi) {
            const int r = wm * 128 + mi * 16 + l15;
            af[mi] = *(const bf16x8*)(sb + r * 64 + ((lhi ^ (r & 3)) * 16));
        }
        #pragma unroll
        for (int ni = 0; ni < 4; ++ni) {
            const int r = wn * 64 + ni * 16 + l15;
            bg[ni] = *(const bf16x8*)(sb + 16384 + r * 64 + ((lhi ^ (r & 3)) * 16));
        }
        asm volatile("s_waitcnt lgkmcnt(0)" ::: "memory");
        __builtin_amdgcn_sched_barrier(0);   // rule 18: keep MFMA below the wait
        __builtin_amdgcn_s_setprio(1);
        #pragma unroll
        for (int mi = 0; mi < 8; ++mi)
            #pragma unroll
            for (int ni = 0; ni < 4; ++ni)
                acc[mi][ni] = __builtin_amdgcn_mfma_f32_16x16x32_bf16(af[mi], bg[ni], acc[mi][ni], 0, 0, 0);
        __builtin_amdgcn_s_setprio(0);
    }

    // epilogue: e = exp2(S * 10*log2e); C/D layout: col=lane&15, row=(lane>>4)*4+reg
    float colsum[4] = {0.0f, 0.0f, 0.0f, 0.0f};
    #pragma unroll
    for (int mi = 0; mi < 8; ++mi) {
        const int growb = rowB + wm * 128 + mi * 16 + lhi * 4;
        float rs[4] = {0.0f, 0.0f, 0.0f, 0.0f};
        if (dg) {
            #pragma unroll
            for (int ni = 0; ni < 4; ++ni) {
                const int gcol = colB + wn * 64 + ni * 16 + l15;
                #pragma unroll
                for (int r = 0; r < 4; ++r) {
                    float arg = acc[mi][ni][r] * SCALE_L2E;
                    if (growb + r == gcol) arg = -1e30f;  // exp2 -> 0 (diagonal mask)
                    rs[r] += exp2f(arg);
                }
            }
        } else {
            #pragma unroll
            for (int ni = 0; ni < 4; ++ni)
                #pragma unroll
                for (int r = 0; r < 4; ++r) {
                    const float e = exp2f(acc[mi][ni][r] * SCALE_L2E);
                    rs[r] += e;
                    colsum[ni] += e;
                }
        }
        // row sums: reduce the 16 lanes sharing lhi; one atomic per (mi, r)
        #pragma unroll
        for (int r = 0; r < 4; ++r) {
            float s = rs[r];
            s += __shfl_xor(s, 1);
            s += __shfl_xor(s, 2);
            s += __shfl_xor(s, 4);
            s += __shfl_xor(s, 8);
            if (l15 == 0) atomicAdd(&rowsum_g[growb + r], s);
        }
    }
    if (!dg) {
        // column sums (symmetry): reduce across lhi groups; lanes lhi==0 hold col l15
        #pragma unroll
        for (int ni = 0; ni < 4; ++ni) {
            float c = colsum[ni];
            c += __shfl_xor(c, 16);
            c += __shfl_xor(c, 32);
            if (lhi == 0)
                atomicAdd(&rowsum_g[colB + wn * 64 + ni * 16 + l15], c);
        }
    }
}

// ---------------- K3: sums[1] += sum(ln(rowsum_i)); sums[0] += sum(pos) ----------------
__global__ __launch_bounds__(256) void k_lse(const float* __restrict__ rowsum_g,
                                             const float* __restrict__ pos,
                                             float* __restrict__ sums) {
    const int i = blockIdx.x * 256 + threadIdx.x;
    float l = logf(rowsum_g[i]);
    float p = (i < B_ROWS) ? pos[i] : 0.0f;
    #pragma unroll
    for (int off = 1; off < 64; off <<= 1) {
        l += __shfl_xor(l, off);
        p += __shfl_xor(p, off);
    }
    __shared__ float red[2][4];
    if ((threadIdx.x & 63) == 0) {
        red[0][threadIdx.x >> 6] = l;
        red[1][threadIdx.x >> 6] = p;
    }
    __syncthreads();
    if (threadIdx.x == 0) {
        atomicAdd(&sums[1], red[0][0] + red[0][1] + red[0][2] + red[0][3]);
        atomicAdd(&sums[0], red[1][0] + red[1][1] + red[1][2] + red[1][3]);
    }
}

// ---------------- K4: loss = mean(lse) - mean(pos) ----------------
__global__ void k_final(const float* __restrict__ sums, float* __restrict__ out) {
    out[0] = (sums[1] - sums[0]) * (1.0f / (float)N_ROWS);
}

extern "C" void kernel_launch(void* const* d_in, const int* in_sizes, int n_in,
                              void* d_out, int out_size, void* d_ws, size_t ws_size,
                              hipStream_t stream) {
    (void)in_sizes; (void)n_in; (void)out_size; (void)ws_size;
    const float* zi = (const float*)d_in[0];
    const float* zj = (const float*)d_in[1];

    // workspace layout
    const size_t ZN_BYTES = (size_t)N_ROWS * D_DIM * 2;  // 8 MiB bf16 (hc-tiled)
    unsigned short* Zn    = (unsigned short*)d_ws;
    float* rowsum_g       = (float*)((char*)d_ws + ZN_BYTES);                           // 8192 f32
    float* pos            = (float*)((char*)d_ws + ZN_BYTES + N_ROWS * 4);              // 4096 f32
    float* sums           = (float*)((char*)d_ws + ZN_BYTES + N_ROWS * 4 + B_ROWS * 4); // [pos, lse]

    // zero the atomically-accumulated region (rowsum + pos + sums)
    hipMemsetAsync((char*)d_ws + ZN_BYTES, 0, N_ROWS * 4 + B_ROWS * 4 + 16, stream);

    k_normalize<<<B_ROWS / 4, 256, 0, stream>>>(zi, zj, Zn, pos);
    k_gemm_lse<<<NPAIRS, 512, 0, stream>>>(Zn, rowsum_g);
    k_lse<<<N_ROWS / 256, 256, 0, stream>>>(rowsum_g, pos, sums);
    k_final<<<1, 1, 0, stream>>>(sums, (float*)d_out);
}

// Round 6
// 99.431 us; speedup vs baseline: 1.0761x; 1.0761x over previous
//
#include <hip/hip_runtime.h>
#include <stdint.h>

// Problem constants
#define D_DIM 512
#define B_ROWS 4096
#define N_ROWS 8192
// (1/TEMPERATURE) * log2(e) : exp(x/T) == exp2(x * SCALE_L2E)
#define SCALE_L2E 14.426950408889634f

#define BM 128                      // tile edge
#define NHC 16                      // half-chunks of K=32
#define NT (N_ROWS / BM)            // 64 tile rows/cols
#define NPAIRS (NT * (NT + 1) / 2)  // 2080
#define TPB 4                       // tile-pairs per block
#define NBLK (NPAIRS / TPB)         // 520 = 8 * 65 (bijective XCD swizzle)
#define NSTEP (TPB * NHC)           // 64 ring steps per block

typedef __attribute__((ext_vector_type(8))) __bf16 bf16x8;
typedef __attribute__((ext_vector_type(4))) float f32x4;

using gas1_t = const __attribute__((address_space(1))) void;
using las3_t = __attribute__((address_space(3))) void;
#define GLOAD16(g, l) __builtin_amdgcn_global_load_lds((gas1_t*)(g), (las3_t*)(l), 16, 0, 0)

// round-to-nearest-even float -> bf16 bits
__device__ __forceinline__ unsigned int f2bf(float f) {
    union { float f; unsigned int u; } v; v.f = f;
    unsigned int u = v.u;
    return (u + 0x7FFFu + ((u >> 16) & 1u)) >> 16;
}

// ---------------- K1: normalize rows -> bf16 Zn (half-chunk-tiled), write positive logits --
// Zn layout: [hc=0..15][row=0..8191][32 bf16] (plane = 512 KiB) so the GEMM stages
// fully-contiguous 4 KiB per gload_lds instruction.
__global__ __launch_bounds__(256) void k_normalize(const float* __restrict__ zi,
                                                   const float* __restrict__ zj,
                                                   unsigned short* __restrict__ Zn,
                                                   float* __restrict__ pos) {
    const int t = threadIdx.x;
    const int lane = t & 63;
    const int i = blockIdx.x * 4 + (t >> 6);
    const float* pa = zi + (size_t)i * D_DIM + lane * 8;
    const float* pb = zj + (size_t)i * D_DIM + lane * 8;
    const float4 a0 = *(const float4*)pa;
    const float4 a1 = *(const float4*)(pa + 4);
    const float4 b0 = *(const float4*)pb;
    const float4 b1 = *(const float4*)(pb + 4);
    float ssi = a0.x*a0.x + a0.y*a0.y + a0.z*a0.z + a0.w*a0.w
              + a1.x*a1.x + a1.y*a1.y + a1.z*a1.z + a1.w*a1.w;
    float ssj = b0.x*b0.x + b0.y*b0.y + b0.z*b0.z + b0.w*b0.w
              + b1.x*b1.x + b1.y*b1.y + b1.z*b1.z + b1.w*b1.w;
    float dt  = a0.x*b0.x + a0.y*b0.y + a0.z*b0.z + a0.w*b0.w
              + a1.x*b1.x + a1.y*b1.y + a1.z*b1.z + a1.w*b1.w;
    #pragma unroll
    for (int off = 1; off < 64; off <<= 1) {
        ssi += __shfl_xor(ssi, off);
        ssj += __shfl_xor(ssj, off);
        dt  += __shfl_xor(dt,  off);
    }
    const float si = 1.0f / fmaxf(sqrtf(ssi), 1e-12f);
    const float sj = 1.0f / fmaxf(sqrtf(ssj), 1e-12f);
    uint4 pi, pj;
    pi.x = f2bf(a0.x * si) | (f2bf(a0.y * si) << 16);
    pi.y = f2bf(a0.z * si) | (f2bf(a0.w * si) << 16);
    pi.z = f2bf(a1.x * si) | (f2bf(a1.y * si) << 16);
    pi.w = f2bf(a1.z * si) | (f2bf(a1.w * si) << 16);
    pj.x = f2bf(b0.x * sj) | (f2bf(b0.y * sj) << 16);
    pj.y = f2bf(b0.z * sj) | (f2bf(b0.w * sj) << 16);
    pj.z = f2bf(b1.x * sj) | (f2bf(b1.y * sj) << 16);
    pj.w = f2bf(b1.z * sj) | (f2bf(b1.w * sj) << 16);
    // lane covers cols lane*8..lane*8+7 -> hc = lane>>2, 16B-seg = lane&3
    const size_t plane = (size_t)N_ROWS * 32;  // elems per hc-plane
    const size_t off0  = (size_t)(lane >> 2) * plane + (lane & 3) * 8;
    *(uint4*)(Zn + off0 + (size_t)i * 32) = pi;
    *(uint4*)(Zn + off0 + (size_t)(B_ROWS + i) * 32) = pj;
    if (lane == 0) pos[i] = 20.0f * dt * si * sj;  // positive logit counted twice: 2*dot/T
}

// ---------------- K2: symmetric fused S = Zn·Zn^T + per-row sum(exp(S/T)) -----------------
// TPB 128x128 tile-pairs (I<=J) per block; 256 threads = 4 waves (2x2), wave tile 64x64.
// 64-step counted-vmcnt ring over K=32 half-chunks; 4 LDS slots of 16 KiB (A 8K + B 8K),
// 64 KiB total -> 2 blocks/CU (TLP). Per step: vmcnt(8) [never drains in steady state] ->
// barrier -> stage(s+3) -> ds_read -> lgkmcnt(0)+sched_barrier -> setprio+16 MFMA.
// Pipeline crosses tile boundaries; per-tile epilogue sits after the last MFMA of a tile.
// LDS layout: paired-row 128B lines: row r at (r>>1)*128 + (r&1)*64, 16B granule
// slot = ks ^ (r&3) (both-sides swizzle) -> conflict-free writes AND b128 reads.
__global__ __launch_bounds__(256, 2) void k_gemm_lse(const unsigned short* __restrict__ Zn,
                                                     float* __restrict__ rowsum_g) {
    __shared__ __align__(16) char lds[4 * 16384];  // 64 KiB: 4 ring slots
    const int t    = threadIdx.x;
    const int lane = t & 63;
    const int w    = t >> 6;
    const int wm   = w >> 1, wn = w & 1;          // 2 x 2 wave grid
    const int l15  = lane & 15, lhi = lane >> 4;

    // XCD-aware swizzle (bijective: NBLK % 8 == 0), then triangular decode of TPB pairs
    const int g = (blockIdx.x & 7) * (NBLK / 8) + (blockIdx.x >> 3);
    int Ia[TPB], Ja[TPB];
    {
        int p = g * TPB, I = 0;
        while (p >= NT - I) { p -= NT - I; ++I; }
        int J = I + p;
        #pragma unroll
        for (int q = 0; q < TPB; ++q) {
            Ia[q] = I; Ja[q] = J;
            ++J; if (J == NT) { ++I; J = I; }
        }
    }
    size_t rb[TPB], cb[TPB];   // panel byte offsets within an hc-plane (const-indexed only)
    #pragma unroll
    for (int q = 0; q < TPB; ++q) {
        rb[q] = (size_t)Ia[q] * (BM * 64);
        cb[q] = (size_t)Ja[q] * (BM * 64);
    }

    const char* Zb = (const char*)Zn;
    const size_t PLANE = (size_t)N_ROWS * 64;  // bytes per hc-plane

    // staging: thread t (u=t>>3, v=t&7) owns LDS byte u*128 + v*16 per 4 KiB instr,
    // i.e. tile row r0 = 2u + (v>>2) (q=0) / r0+64 (q=1), granule slot v&3.
    // stored K-seg at (r, slot s) is s ^ (r&3)  => source byte = r*64 + (s^(r&3))*16.
    const int r0   = 2 * (t >> 3) + ((t & 7) >> 2);
    const int off0 = r0 * 64 + (((t & 3) ^ (r0 & 3)) << 4);

    auto stage = [&](int slot, size_t aOff, size_t bOff) {
        char* sb = (char*)lds + slot * 16384;
        GLOAD16(Zb + aOff + off0,        sb + t * 16);
        GLOAD16(Zb + aOff + off0 + 4096, sb + 4096 + t * 16);
        GLOAD16(Zb + bOff + off0,        sb + 8192 + t * 16);
        GLOAD16(Zb + bOff + off0 + 4096, sb + 12288 + t * 16);
    };

    // fragment read bases (step-invariant): row r = rr + mi*16
    // addr = (r>>1)*128 + (r&1)*64 + ((lhi^(r&3))<<4) = base + mi*1024
    const int rrA = wm * 64 + l15;
    const int ArdBase = ((rrA >> 1) * 128) + ((rrA & 1) * 64) + ((lhi ^ (rrA & 3)) << 4);
    const int rrB = wn * 64 + l15;
    const int BrdBase = 8192 + ((rrB >> 1) * 128) + ((rrB & 1) * 64) + ((lhi ^ (rrB & 3)) << 4);

    f32x4 acc[4][4];
    #pragma unroll
    for (int a = 0; a < 4; ++a)
        #pragma unroll
        for (int b = 0; b < 4; ++b)
            #pragma unroll
            for (int q = 0; q < 4; ++q) acc[a][b][q] = 0.0f;

    // prologue: 3 steps in flight (all tile 0)
    stage(0, rb[0] + 0 * PLANE, cb[0] + 0 * PLANE);
    stage(1, rb[0] + 1 * PLANE, cb[0] + 1 * PLANE);
    stage(2, rb[0] + 2 * PLANE, cb[0] + 2 * PLANE);

    #pragma unroll
    for (int ti = 0; ti < TPB; ++ti) {
        #pragma unroll
        for (int kc = 0; kc < NHC; ++kc) {
            const int s = ti * NHC + kc;
            // wait for stage(s): keep later stages in flight (counted, never early-drain)
            if (s <= NSTEP - 3)      asm volatile("s_waitcnt vmcnt(8)" ::: "memory");
            else if (s == NSTEP - 2) asm volatile("s_waitcnt vmcnt(4)" ::: "memory");
            else                     asm volatile("s_waitcnt vmcnt(0)" ::: "memory");
            __builtin_amdgcn_sched_barrier(0);
            __builtin_amdgcn_s_barrier();
            __builtin_amdgcn_sched_barrier(0);
            if (s + 3 < NSTEP) {
                const int sn = s + 3, tn = sn >> 4, hn = sn & 15;
                stage(sn & 3, rb[tn] + (size_t)hn * PLANE, cb[tn] + (size_t)hn * PLANE);
            }

            const char* sb = (const char*)lds + (s & 3) * 16384;
            bf16x8 af[4], bg[4];
            #pragma unroll
            for (int mi = 0; mi < 4; ++mi)
                af[mi] = *(const bf16x8*)(sb + ArdBase + mi * 1024);
            #pragma unroll
            for (int ni = 0; ni < 4; ++ni)
                bg[ni] = *(const bf16x8*)(sb + BrdBase + ni * 1024);
            asm volatile("s_waitcnt lgkmcnt(0)" ::: "memory");
            __builtin_amdgcn_sched_barrier(0);   // rule 18: keep MFMA below the wait
            __builtin_amdgcn_s_setprio(1);
            #pragma unroll
            for (int mi = 0; mi < 4; ++mi)
                #pragma unroll
                for (int ni = 0; ni < 4; ++ni)
                    acc[mi][ni] = __builtin_amdgcn_mfma_f32_16x16x32_bf16(af[mi], bg[ni], acc[mi][ni], 0, 0, 0);
            __builtin_amdgcn_s_setprio(0);

            if (kc == NHC - 1) {
                // ---- per-tile epilogue: e = exp2(S*10*log2e); C/D: col=l15, row=lhi*4+reg
                const int rowB = Ia[ti] * BM, colB = Ja[ti] * BM;
                const bool dg = (Ia[ti] == Ja[ti]);
                float colsum[4] = {0.0f, 0.0f, 0.0f, 0.0f};
                #pragma unroll
                for (int mi = 0; mi < 4; ++mi) {
                    const int growb = rowB + wm * 64 + mi * 16 + lhi * 4;
                    float rs[4] = {0.0f, 0.0f, 0.0f, 0.0f};
                    if (dg) {
                        #pragma unroll
                        for (int ni = 0; ni < 4; ++ni) {
                            const int gcol = colB + wn * 64 + ni * 16 + l15;
                            #pragma unroll
                            for (int r = 0; r < 4; ++r) {
                                float arg = acc[mi][ni][r] * SCALE_L2E;
                                if (growb + r == gcol) arg = -1e30f;  // diagonal mask
                                rs[r] += exp2f(arg);
                            }
                        }
                    } else {
                        #pragma unroll
                        for (int ni = 0; ni < 4; ++ni)
                            #pragma unroll
                            for (int r = 0; r < 4; ++r) {
                                const float e = exp2f(acc[mi][ni][r] * SCALE_L2E);
                                rs[r] += e;
                                colsum[ni] += e;
                            }
                    }
                    #pragma unroll
                    for (int r = 0; r < 4; ++r) {
                        float v = rs[r];
                        v += __shfl_xor(v, 1);
                        v += __shfl_xor(v, 2);
                        v += __shfl_xor(v, 4);
                        v += __shfl_xor(v, 8);
                        if (l15 == 0) atomicAdd(&rowsum_g[growb + r], v);
                    }
                }
                if (!dg) {
                    #pragma unroll
                    for (int ni = 0; ni < 4; ++ni) {
                        float c = colsum[ni];
                        c += __shfl_xor(c, 16);
                        c += __shfl_xor(c, 32);
                        if (lhi == 0)
                            atomicAdd(&rowsum_g[colB + wn * 64 + ni * 16 + l15], c);
                    }
                }
                // reset accumulators for the next tile
                #pragma unroll
                for (int a = 0; a < 4; ++a)
                    #pragma unroll
                    for (int b = 0; b < 4; ++b)
                        #pragma unroll
                        for (int q = 0; q < 4; ++q) acc[a][b][q] = 0.0f;
            }
        }
    }
}

// ---------------- K3: sums[1] += sum(ln(rowsum_i)); sums[0] += sum(pos) ----------------
__global__ __launch_bounds__(256) void k_lse(const float* __restrict__ rowsum_g,
                                             const float* __restrict__ pos,
                                             float* __restrict__ sums) {
    const int i = blockIdx.x * 256 + threadIdx.x;
    float l = logf(rowsum_g[i]);
    float p = (i < B_ROWS) ? pos[i] : 0.0f;
    #pragma unroll
    for (int off = 1; off < 64; off <<= 1) {
        l += __shfl_xor(l, off);
        p += __shfl_xor(p, off);
    }
    __shared__ float red[2][4];
    if ((threadIdx.x & 63) == 0) {
        red[0][threadIdx.x >> 6] = l;
        red[1][threadIdx.x >> 6] = p;
    }
    __syncthreads();
    if (threadIdx.x == 0) {
        atomicAdd(&sums[1], red[0][0] + red[0][1] + red[0][2] + red[0][3]);
        atomicAdd(&sums[0], red[1][0] + red[1][1] + red[1][2] + red[1][3]);
    }
}

// ---------------- K4: loss = mean(lse) - mean(pos) ----------------
__global__ void k_final(const float* __restrict__ sums, float* __restrict__ out) {
    out[0] = (sums[1] - sums[0]) * (1.0f / (float)N_ROWS);
}

extern "C" void kernel_launch(void* const* d_in, const int* in_sizes, int n_in,
                              void* d_out, int out_size, void* d_ws, size_t ws_size,
                              hipStream_t stream) {
    (void)in_sizes; (void)n_in; (void)out_size; (void)ws_size;
    const float* zi = (const float*)d_in[0];
    const float* zj = (const float*)d_in[1];

    // workspace layout
    const size_t ZN_BYTES = (size_t)N_ROWS * D_DIM * 2;  // 8 MiB bf16 (hc-tiled)
    unsigned short* Zn    = (unsigned short*)d_ws;
    float* rowsum_g       = (float*)((char*)d_ws + ZN_BYTES);                           // 8192 f32
    float* pos            = (float*)((char*)d_ws + ZN_BYTES + N_ROWS * 4);              // 4096 f32
    float* sums           = (float*)((char*)d_ws + ZN_BYTES + N_ROWS * 4 + B_ROWS * 4); // [pos, lse]

    // zero the atomically-accumulated region (rowsum + pos + sums)
    hipMemsetAsync((char*)d_ws + ZN_BYTES, 0, N_ROWS * 4 + B_ROWS * 4 + 16, stream);

    k_normalize<<<B_ROWS / 4, 256, 0, stream>>>(zi, zj, Zn, pos);
    k_gemm_lse<<<NBLK, 256, 0, stream>>>(Zn, rowsum_g);
    k_lse<<<N_ROWS / 256, 256, 0, stream>>>(rowsum_g, pos, sums);
    k_final<<<1, 1, 0, stream>>>(sums, (float*)d_out);
}

// Round 7
// 92.568 us; speedup vs baseline: 1.1558x; 1.0741x over previous
//
#include <hip/hip_runtime.h>
#include <stdint.h>

// Problem constants
#define D_DIM 512
#define B_ROWS 4096
#define N_ROWS 8192
// (1/TEMPERATURE) * log2(e) : exp(x/T) == exp2(x * SCALE_L2E)
#define SCALE_L2E 14.426950408889634f

#define NHC 16                      // half-chunks of K=32
// Block tile: 256 rows (I2 band = two 128-tiles) x 128 cols (one 128-tile col J).
// Blocks enumerate (I2, J) with J >= 2*I2: sum_{I2=0}^{31} (64-2*I2) = 1056.
#define NBLK 1056                   // divisible by 8 (bijective XCD swizzle)

typedef __attribute__((ext_vector_type(8))) __bf16 bf16x8;
typedef __attribute__((ext_vector_type(4))) float f32x4;

// round-to-nearest-even float -> bf16 bits
__device__ __forceinline__ unsigned int f2bf(float f) {
    union { float f; unsigned int u; } v; v.f = f;
    unsigned int u = v.u;
    return (u + 0x7FFFu + ((u >> 16) & 1u)) >> 16;
}

// ---------------- K1: normalize rows -> bf16 Zn (half-chunk-tiled), write positive logits --
// Zn layout: [hc=0..15][row=0..8191][32 bf16] (plane = 512 KiB). An MFMA fragment read
// (lanes: row=l15, kseg=lhi) is then a fully-contiguous, perfectly-coalesced 1 KiB segment.
__global__ __launch_bounds__(256) void k_normalize(const float* __restrict__ zi,
                                                   const float* __restrict__ zj,
                                                   unsigned short* __restrict__ Zn,
                                                   float* __restrict__ pos) {
    const int t = threadIdx.x;
    const int lane = t & 63;
    const int i = blockIdx.x * 4 + (t >> 6);
    const float* pa = zi + (size_t)i * D_DIM + lane * 8;
    const float* pb = zj + (size_t)i * D_DIM + lane * 8;
    const float4 a0 = *(const float4*)pa;
    const float4 a1 = *(const float4*)(pa + 4);
    const float4 b0 = *(const float4*)pb;
    const float4 b1 = *(const float4*)(pb + 4);
    float ssi = a0.x*a0.x + a0.y*a0.y + a0.z*a0.z + a0.w*a0.w
              + a1.x*a1.x + a1.y*a1.y + a1.z*a1.z + a1.w*a1.w;
    float ssj = b0.x*b0.x + b0.y*b0.y + b0.z*b0.z + b0.w*b0.w
              + b1.x*b1.x + b1.y*b1.y + b1.z*b1.z + b1.w*b1.w;
    float dt  = a0.x*b0.x + a0.y*b0.y + a0.z*b0.z + a0.w*b0.w
              + a1.x*b1.x + a1.y*b1.y + a1.z*b1.z + a1.w*b1.w;
    #pragma unroll
    for (int off = 1; off < 64; off <<= 1) {
        ssi += __shfl_xor(ssi, off);
        ssj += __shfl_xor(ssj, off);
        dt  += __shfl_xor(dt,  off);
    }
    const float si = 1.0f / fmaxf(sqrtf(ssi), 1e-12f);
    const float sj = 1.0f / fmaxf(sqrtf(ssj), 1e-12f);
    uint4 pi, pj;
    pi.x = f2bf(a0.x * si) | (f2bf(a0.y * si) << 16);
    pi.y = f2bf(a0.z * si) | (f2bf(a0.w * si) << 16);
    pi.z = f2bf(a1.x * si) | (f2bf(a1.y * si) << 16);
    pi.w = f2bf(a1.z * si) | (f2bf(a1.w * si) << 16);
    pj.x = f2bf(b0.x * sj) | (f2bf(b0.y * sj) << 16);
    pj.y = f2bf(b0.z * sj) | (f2bf(b0.w * sj) << 16);
    pj.z = f2bf(b1.x * sj) | (f2bf(b1.y * sj) << 16);
    pj.w = f2bf(b1.z * sj) | (f2bf(b1.w * sj) << 16);
    // lane covers cols lane*8..lane*8+7 -> hc = lane>>2, 16B-seg = lane&3
    const size_t plane = (size_t)N_ROWS * 32;  // elems per hc-plane
    const size_t off0  = (size_t)(lane >> 2) * plane + (lane & 3) * 8;
    *(uint4*)(Zn + off0 + (size_t)i * 32) = pi;
    *(uint4*)(Zn + off0 + (size_t)(B_ROWS + i) * 32) = pj;
    if (lane == 0) pos[i] = 20.0f * dt * si * sj;  // positive logit counted twice: 2*dot/T
}

// ---------------- K2: symmetric fused S = Zn·Zn^T + per-row sum(exp(S/T)) -----------------
// NO LDS, NO BARRIERS. Each wave loads its MFMA fragments directly global->VGPR (perfectly
// coalesced via the hc-tiled layout; data is L2/L3-resident at 8 MiB). 256 threads = 4
// independent waves (2x2), wave tile 128x64, block tile 256x128. 2-stage register
// double-buffer across hc (explicit a0/a1 alternation, all static indexing).
// Waves whose 128-tile (I = 2*I2+wm) falls below the diagonal (I > J) exit early.
__global__ __launch_bounds__(256, 2) void k_gemm_lse(const unsigned short* __restrict__ Zn,
                                                     float* __restrict__ rowsum_g) {
    const int t    = threadIdx.x;
    const int lane = t & 63;
    const int w    = t >> 6;
    const int wm   = w >> 1, wn = w & 1;          // 2 x 2 wave grid
    const int l15  = lane & 15, lhi = lane >> 4;

    // XCD-aware swizzle (bijective: NBLK % 8 == 0), then (I2, J) decode
    int g = (blockIdx.x & 7) * (NBLK / 8) + (blockIdx.x >> 3);
    int I2 = 0;
    while (g >= 64 - 2 * I2) { g -= 64 - 2 * I2; ++I2; }
    const int J = 2 * I2 + g;

    const int myI  = 2 * I2 + wm;          // this wave's 128-row tile index
    if (myI > J) return;                   // below diagonal: nothing to do (wave-uniform)
    const bool dg  = (myI == J);
    const int rowB = I2 * 256 + wm * 128;  // wave's first output row
    const int colB = J * 128 + wn * 64;    // wave's first output col

    const char* Zb = (const char*)Zn;
    const size_t PLANE = (size_t)N_ROWS * 64;  // bytes per hc-plane

    // fragment base pointers: lane (lhi,l15) reads row (base + l15 + 16*frag), k-seg lhi
    const char* pA = Zb + ((size_t)(rowB + l15)) * 64 + lhi * 16;
    const char* pB = Zb + ((size_t)(colB + l15)) * 64 + lhi * 16;

    bf16x8 a0[8], b0[4], a1[8], b1[4];

#define LOADAB(dstA, dstB, hc)                                                   \
    do {                                                                         \
        const char* _a = pA + (size_t)(hc) * PLANE;                              \
        const char* _b = pB + (size_t)(hc) * PLANE;                              \
        _Pragma("unroll")                                                        \
        for (int mi = 0; mi < 8; ++mi) dstA[mi] = *(const bf16x8*)(_a + mi * 1024); \
        _Pragma("unroll")                                                        \
        for (int ni = 0; ni < 4; ++ni) dstB[ni] = *(const bf16x8*)(_b + ni * 1024); \
    } while (0)

#define MFMAAB(srcA, srcB)                                                       \
    do {                                                                         \
        __builtin_amdgcn_s_setprio(1);                                           \
        _Pragma("unroll")                                                        \
        for (int mi = 0; mi < 8; ++mi)                                           \
            _Pragma("unroll")                                                    \
            for (int ni = 0; ni < 4; ++ni)                                       \
                acc[mi][ni] = __builtin_amdgcn_mfma_f32_16x16x32_bf16(           \
                    srcA[mi], srcB[ni], acc[mi][ni], 0, 0, 0);                   \
        __builtin_amdgcn_s_setprio(0);                                           \
    } while (0)

    f32x4 acc[8][4];
    #pragma unroll
    for (int a = 0; a < 8; ++a)
        #pragma unroll
        for (int b = 0; b < 4; ++b)
            #pragma unroll
            for (int q = 0; q < 4; ++q) acc[a][b][q] = 0.0f;

    // 2-stage register pipeline over the 16 half-chunks
    LOADAB(a0, b0, 0);
    LOADAB(a1, b1, 1);
    #pragma unroll
    for (int hp = 0; hp < NHC / 2; ++hp) {
        MFMAAB(a0, b0);
        if (hp < NHC / 2 - 1) LOADAB(a0, b0, 2 * hp + 2);
        MFMAAB(a1, b1);
        if (hp < NHC / 2 - 1) LOADAB(a1, b1, 2 * hp + 3);
    }

    // epilogue: e = exp2(S * 10*log2e); C/D layout: col=lane&15, row=(lane>>4)*4+reg
    float colsum[4] = {0.0f, 0.0f, 0.0f, 0.0f};
    #pragma unroll
    for (int mi = 0; mi < 8; ++mi) {
        const int growb = rowB + mi * 16 + lhi * 4;
        float rs[4] = {0.0f, 0.0f, 0.0f, 0.0f};
        if (dg) {
            #pragma unroll
            for (int ni = 0; ni < 4; ++ni) {
                const int gcol = colB + ni * 16 + l15;
                #pragma unroll
                for (int r = 0; r < 4; ++r) {
                    float arg = acc[mi][ni][r] * SCALE_L2E;
                    if (growb + r == gcol) arg = -1e30f;  // diagonal mask -> exp2 = 0
                    rs[r] += exp2f(arg);
                }
            }
        } else {
            #pragma unroll
            for (int ni = 0; ni < 4; ++ni)
                #pragma unroll
                for (int r = 0; r < 4; ++r) {
                    const float e = exp2f(acc[mi][ni][r] * SCALE_L2E);
                    rs[r] += e;
                    colsum[ni] += e;
                }
        }
        // row sums: reduce the 16 lanes sharing lhi; one atomic per (mi, r)
        #pragma unroll
        for (int r = 0; r < 4; ++r) {
            float v = rs[r];
            v += __shfl_xor(v, 1);
            v += __shfl_xor(v, 2);
            v += __shfl_xor(v, 4);
            v += __shfl_xor(v, 8);
            if (l15 == 0) atomicAdd(&rowsum_g[growb + r], v);
        }
    }
    if (!dg) {
        // column sums (symmetry): reduce across lhi groups; lanes lhi==0 hold col l15
        #pragma unroll
        for (int ni = 0; ni < 4; ++ni) {
            float c = colsum[ni];
            c += __shfl_xor(c, 16);
            c += __shfl_xor(c, 32);
            if (lhi == 0)
                atomicAdd(&rowsum_g[colB + ni * 16 + l15], c);
        }
    }
#undef LOADAB
#undef MFMAAB
}

// ---------------- K3: sums[1] += sum(ln(rowsum_i)); sums[0] += sum(pos) ----------------
__global__ __launch_bounds__(256) void k_lse(const float* __restrict__ rowsum_g,
                                             const float* __restrict__ pos,
                                             float* __restrict__ sums) {
    const int i = blockIdx.x * 256 + threadIdx.x;
    float l = logf(rowsum_g[i]);
    float p = (i < B_ROWS) ? pos[i] : 0.0f;
    #pragma unroll
    for (int off = 1; off < 64; off <<= 1) {
        l += __shfl_xor(l, off);
        p += __shfl_xor(p, off);
    }
    __shared__ float red[2][4];
    if ((threadIdx.x & 63) == 0) {
        red[0][threadIdx.x >> 6] = l;
        red[1][threadIdx.x >> 6] = p;
    }
    __syncthreads();
    if (threadIdx.x == 0) {
        atomicAdd(&sums[1], red[0][0] + red[0][1] + red[0][2] + red[0][3]);
        atomicAdd(&sums[0], red[1][0] + red[1][1] + red[1][2] + red[1][3]);
    }
}

// ---------------- K4: loss = mean(lse) - mean(pos) ----------------
__global__ void k_final(const float* __restrict__ sums, float* __restrict__ out) {
    out[0] = (sums[1] - sums[0]) * (1.0f / (float)N_ROWS);
}

extern "C" void kernel_launch(void* const* d_in, const int* in_sizes, int n_in,
                              void* d_out, int out_size, void* d_ws, size_t ws_size,
                              hipStream_t stream) {
    (void)in_sizes; (void)n_in; (void)out_size; (void)ws_size;
    const float* zi = (const float*)d_in[0];
    const float* zj = (const float*)d_in[1];

    // workspace layout
    const size_t ZN_BYTES = (size_t)N_ROWS * D_DIM * 2;  // 8 MiB bf16 (hc-tiled)
    unsigned short* Zn    = (unsigned short*)d_ws;
    float* rowsum_g       = (float*)((char*)d_ws + ZN_BYTES);                           // 8192 f32
    float* pos            = (float*)((char*)d_ws + ZN_BYTES + N_ROWS * 4);              // 4096 f32
    float* sums           = (float*)((char*)d_ws + ZN_BYTES + N_ROWS * 4 + B_ROWS * 4); // [pos, lse]

    // zero the atomically-accumulated region (rowsum + pos + sums)
    hipMemsetAsync((char*)d_ws + ZN_BYTES, 0, N_ROWS * 4 + B_ROWS * 4 + 16, stream);

    k_normalize<<<B_ROWS / 4, 256, 0, stream>>>(zi, zj, Zn, pos);
    k_gemm_lse<<<NBLK, 256, 0, stream>>>(Zn, rowsum_g);
    k_lse<<<N_ROWS / 256, 256, 0, stream>>>(rowsum_g, pos, sums);
    k_final<<<1, 1, 0, stream>>>(sums, (float*)d_out);
}

// Round 8
// 78.481 us; speedup vs baseline: 1.3633x; 1.1795x over previous
//
#include <hip/hip_runtime.h>
#include <stdint.h>

// Problem constants
#define D_DIM 512
#define B_ROWS 4096
#define N_ROWS 8192
// (1/TEMPERATURE) * log2(e) : exp(x/T) == exp2(x * SCALE_L2E)
#define SCALE_L2E 14.426950408889634f

#define NHC 16                      // half-chunks of K=32
// Block tile: 256 rows (I2 band = two 128-tiles) x 128 cols (one 128-tile col J).
// Blocks enumerate (I2, J) with J >= 2*I2: sum_{I2=0}^{31} (64-2*I2) = 1056.
#define NBLK 1056                   // divisible by 8 (bijective XCD swizzle)

typedef __attribute__((ext_vector_type(4))) float f32x4;
typedef long f8x8;                  // 8 fp8 bytes = 2 VGPRs (MFMA A/B operand)

// ---------------- K1: normalize rows -> fp8 e4m3 Zn (half-chunk-tiled), fp32 pos logits ----
// Zn layout: [hc=0..15][row=0..8191][32 fp8] (plane = 256 KiB, total 4 MiB -> fits in one
// XCD L2). MFMA fragment read (row=l15+16*mi, kseg=lhi) = contiguous coalesced 512 B.
__global__ __launch_bounds__(256) void k_normalize(const float* __restrict__ zi,
                                                   const float* __restrict__ zj,
                                                   unsigned char* __restrict__ Zn,
                                                   float* __restrict__ pos) {
    const int t = threadIdx.x;
    const int lane = t & 63;
    const int i = blockIdx.x * 4 + (t >> 6);
    const float* pa = zi + (size_t)i * D_DIM + lane * 8;
    const float* pb = zj + (size_t)i * D_DIM + lane * 8;
    const float4 a0 = *(const float4*)pa;
    const float4 a1 = *(const float4*)(pa + 4);
    const float4 b0 = *(const float4*)pb;
    const float4 b1 = *(const float4*)(pb + 4);
    float ssi = a0.x*a0.x + a0.y*a0.y + a0.z*a0.z + a0.w*a0.w
              + a1.x*a1.x + a1.y*a1.y + a1.z*a1.z + a1.w*a1.w;
    float ssj = b0.x*b0.x + b0.y*b0.y + b0.z*b0.z + b0.w*b0.w
              + b1.x*b1.x + b1.y*b1.y + b1.z*b1.z + b1.w*b1.w;
    float dt  = a0.x*b0.x + a0.y*b0.y + a0.z*b0.z + a0.w*b0.w
              + a1.x*b1.x + a1.y*b1.y + a1.z*b1.z + a1.w*b1.w;
    #pragma unroll
    for (int off = 1; off < 64; off <<= 1) {
        ssi += __shfl_xor(ssi, off);
        ssj += __shfl_xor(ssj, off);
        dt  += __shfl_xor(dt,  off);
    }
    const float si = 1.0f / fmaxf(sqrtf(ssi), 1e-12f);
    const float sj = 1.0f / fmaxf(sqrtf(ssj), 1e-12f);
    // pack 8 normalized values -> 8 fp8 e4m3 (HW RNE via v_cvt_pk_fp8_f32)
    uint2 pi8, pj8;
    {
        int w0 = 0, w1 = 0;
        w0 = __builtin_amdgcn_cvt_pk_fp8_f32(a0.x * si, a0.y * si, w0, false);
        w0 = __builtin_amdgcn_cvt_pk_fp8_f32(a0.z * si, a0.w * si, w0, true);
        w1 = __builtin_amdgcn_cvt_pk_fp8_f32(a1.x * si, a1.y * si, w1, false);
        w1 = __builtin_amdgcn_cvt_pk_fp8_f32(a1.z * si, a1.w * si, w1, true);
        pi8.x = (unsigned)w0; pi8.y = (unsigned)w1;
        w0 = 0; w1 = 0;
        w0 = __builtin_amdgcn_cvt_pk_fp8_f32(b0.x * sj, b0.y * sj, w0, false);
        w0 = __builtin_amdgcn_cvt_pk_fp8_f32(b0.z * sj, b0.w * sj, w0, true);
        w1 = __builtin_amdgcn_cvt_pk_fp8_f32(b1.x * sj, b1.y * sj, w1, false);
        w1 = __builtin_amdgcn_cvt_pk_fp8_f32(b1.z * sj, b1.w * sj, w1, true);
        pj8.x = (unsigned)w0; pj8.y = (unsigned)w1;
    }
    // lane covers cols lane*8..lane*8+7 -> hc = lane>>2, 8B-seg = lane&3
    const size_t plane = (size_t)N_ROWS * 32;  // bytes per hc-plane
    const size_t off0  = (size_t)(lane >> 2) * plane + (lane & 3) * 8;
    *(uint2*)(Zn + off0 + (size_t)i * 32) = pi8;
    *(uint2*)(Zn + off0 + (size_t)(B_ROWS + i) * 32) = pj8;
    if (lane == 0) pos[i] = 20.0f * dt * si * sj;  // positive logit counted twice: 2*dot/T
}

// ---------------- K2: symmetric fused S = Zn·Zn^T (fp8 MFMA) + per-row sum(exp(S/T)) ------
// NO LDS, NO BARRIERS. Fragments load directly global->VGPR, perfectly coalesced via the
// hc-tiled fp8 layout; the 4 MiB matrix is L2-resident per XCD. 256 threads = 4 independent
// waves (2x2), wave tile 128x64, block tile 256x128. 2-stage register double-buffer.
// Waves whose 128-tile (I = 2*I2+wm) falls below the diagonal (I > J) exit early.
__global__ __launch_bounds__(256, 2) void k_gemm_lse(const unsigned char* __restrict__ Zn,
                                                     float* __restrict__ rowsum_g) {
    const int t    = threadIdx.x;
    const int lane = t & 63;
    const int w    = t >> 6;
    const int wm   = w >> 1, wn = w & 1;          // 2 x 2 wave grid
    const int l15  = lane & 15, lhi = lane >> 4;

    // XCD-aware swizzle (bijective: NBLK % 8 == 0), then (I2, J) decode
    int g = (blockIdx.x & 7) * (NBLK / 8) + (blockIdx.x >> 3);
    int I2 = 0;
    while (g >= 64 - 2 * I2) { g -= 64 - 2 * I2; ++I2; }
    const int J = 2 * I2 + g;

    const int myI  = 2 * I2 + wm;          // this wave's 128-row tile index
    if (myI > J) return;                   // below diagonal: nothing to do (wave-uniform)
    const bool dg  = (myI == J);
    const int rowB = I2 * 256 + wm * 128;  // wave's first output row
    const int colB = J * 128 + wn * 64;    // wave's first output col

    const char* Zb = (const char*)Zn;
    const size_t PLANE = (size_t)N_ROWS * 32;  // bytes per hc-plane

    // fragment base pointers: lane (lhi,l15) reads row (base + l15 + 16*frag), k-seg lhi
    const char* pA = Zb + ((size_t)(rowB + l15)) * 32 + lhi * 8;
    const char* pB = Zb + ((size_t)(colB + l15)) * 32 + lhi * 8;

    f8x8 a0[8], b0[4], a1[8], b1[4];

#define LOADAB(dstA, dstB, hc)                                                   \
    do {                                                                         \
        const char* _a = pA + (size_t)(hc) * PLANE;                              \
        const char* _b = pB + (size_t)(hc) * PLANE;                              \
        _Pragma("unroll")                                                        \
        for (int mi = 0; mi < 8; ++mi) dstA[mi] = *(const f8x8*)(_a + mi * 512); \
        _Pragma("unroll")                                                        \
        for (int ni = 0; ni < 4; ++ni) dstB[ni] = *(const f8x8*)(_b + ni * 512); \
    } while (0)

#define MFMAAB(srcA, srcB)                                                       \
    do {                                                                         \
        __builtin_amdgcn_s_setprio(1);                                           \
        _Pragma("unroll")                                                        \
        for (int mi = 0; mi < 8; ++mi)                                           \
            _Pragma("unroll")                                                    \
            for (int ni = 0; ni < 4; ++ni)                                       \
                acc[mi][ni] = __builtin_amdgcn_mfma_f32_16x16x32_fp8_fp8(        \
                    srcA[mi], srcB[ni], acc[mi][ni], 0, 0, 0);                   \
        __builtin_amdgcn_s_setprio(0);                                           \
    } while (0)

    f32x4 acc[8][4];
    #pragma unroll
    for (int a = 0; a < 8; ++a)
        #pragma unroll
        for (int b = 0; b < 4; ++b)
            #pragma unroll
            for (int q = 0; q < 4; ++q) acc[a][b][q] = 0.0f;

    // 2-stage register pipeline over the 16 half-chunks
    LOADAB(a0, b0, 0);
    LOADAB(a1, b1, 1);
    #pragma unroll
    for (int hp = 0; hp < NHC / 2; ++hp) {
        MFMAAB(a0, b0);
        if (hp < NHC / 2 - 1) LOADAB(a0, b0, 2 * hp + 2);
        MFMAAB(a1, b1);
        if (hp < NHC / 2 - 1) LOADAB(a1, b1, 2 * hp + 3);
    }

    // epilogue: e = exp2(S * 10*log2e); C/D layout: col=lane&15, row=(lane>>4)*4+reg
    float colsum[4] = {0.0f, 0.0f, 0.0f, 0.0f};
    #pragma unroll
    for (int mi = 0; mi < 8; ++mi) {
        const int growb = rowB + mi * 16 + lhi * 4;
        float rs[4] = {0.0f, 0.0f, 0.0f, 0.0f};
        if (dg) {
            #pragma unroll
            for (int ni = 0; ni < 4; ++ni) {
                const int gcol = colB + ni * 16 + l15;
                #pragma unroll
                for (int r = 0; r < 4; ++r) {
                    float arg = acc[mi][ni][r] * SCALE_L2E;
                    if (growb + r == gcol) arg = -1e30f;  // diagonal mask -> exp2 = 0
                    rs[r] += exp2f(arg);
                }
            }
        } else {
            #pragma unroll
            for (int ni = 0; ni < 4; ++ni)
                #pragma unroll
                for (int r = 0; r < 4; ++r) {
                    const float e = exp2f(acc[mi][ni][r] * SCALE_L2E);
                    rs[r] += e;
                    colsum[ni] += e;
                }
        }
        // row sums: reduce the 16 lanes sharing lhi; one atomic per (mi, r)
        #pragma unroll
        for (int r = 0; r < 4; ++r) {
            float v = rs[r];
            v += __shfl_xor(v, 1);
            v += __shfl_xor(v, 2);
            v += __shfl_xor(v, 4);
            v += __shfl_xor(v, 8);
            if (l15 == 0) atomicAdd(&rowsum_g[growb + r], v);
        }
    }
    if (!dg) {
        // column sums (symmetry): reduce across lhi groups; lanes lhi==0 hold col l15
        #pragma unroll
        for (int ni = 0; ni < 4; ++ni) {
            float c = colsum[ni];
            c += __shfl_xor(c, 16);
            c += __shfl_xor(c, 32);
            if (lhi == 0)
                atomicAdd(&rowsum_g[colB + ni * 16 + l15], c);
        }
    }
#undef LOADAB
#undef MFMAAB
}

// ---------------- K3: sums[1] += sum(ln(rowsum_i)); sums[0] += sum(pos) ----------------
__global__ __launch_bounds__(256) void k_lse(const float* __restrict__ rowsum_g,
                                             const float* __restrict__ pos,
                                             float* __restrict__ sums) {
    const int i = blockIdx.x * 256 + threadIdx.x;
    float l = logf(rowsum_g[i]);
    float p = (i < B_ROWS) ? pos[i] : 0.0f;
    #pragma unroll
    for (int off = 1; off < 64; off <<= 1) {
        l += __shfl_xor(l, off);
        p += __shfl_xor(p, off);
    }
    __shared__ float red[2][4];
    if ((threadIdx.x & 63) == 0) {
        red[0][threadIdx.x >> 6] = l;
        red[1][threadIdx.x >> 6] = p;
    }
    __syncthreads();
    if (threadIdx.x == 0) {
        atomicAdd(&sums[1], red[0][0] + red[0][1] + red[0][2] + red[0][3]);
        atomicAdd(&sums[0], red[1][0] + red[1][1] + red[1][2] + red[1][3]);
    }
}

// ---------------- K4: loss = mean(lse) - mean(pos) ----------------
__global__ void k_final(const float* __restrict__ sums, float* __restrict__ out) {
    out[0] = (sums[1] - sums[0]) * (1.0f / (float)N_ROWS);
}

extern "C" void kernel_launch(void* const* d_in, const int* in_sizes, int n_in,
                              void* d_out, int out_size, void* d_ws, size_t ws_size,
                              hipStream_t stream) {
    (void)in_sizes; (void)n_in; (void)out_size; (void)ws_size;
    const float* zi = (const float*)d_in[0];
    const float* zj = (const float*)d_in[1];

    // workspace layout
    const size_t ZN_BYTES = (size_t)N_ROWS * D_DIM;  // 4 MiB fp8 (hc-tiled)
    unsigned char* Zn     = (unsigned char*)d_ws;
    float* rowsum_g       = (float*)((char*)d_ws + ZN_BYTES);                           // 8192 f32
    float* pos            = (float*)((char*)d_ws + ZN_BYTES + N_ROWS * 4);              // 4096 f32
    float* sums           = (float*)((char*)d_ws + ZN_BYTES + N_ROWS * 4 + B_ROWS * 4); // [pos, lse]

    // zero the atomically-accumulated region (rowsum + pos + sums)
    hipMemsetAsync((char*)d_ws + ZN_BYTES, 0, N_ROWS * 4 + B_ROWS * 4 + 16, stream);

    k_normalize<<<B_ROWS / 4, 256, 0, stream>>>(zi, zj, Zn, pos);
    k_gemm_lse<<<NBLK, 256, 0, stream>>>(Zn, rowsum_g);
    k_lse<<<N_ROWS / 256, 256, 0, stream>>>(rowsum_g, pos, sums);
    k_final<<<1, 1, 0, stream>>>(sums, (float*)d_out);
}

// Round 9
// 78.139 us; speedup vs baseline: 1.3693x; 1.0044x over previous
//
#include <hip/hip_runtime.h>
#include <stdint.h>

// Problem constants
#define D_DIM 512
#define B_ROWS 4096
#define N_ROWS 8192
// (1/TEMPERATURE) * log2(e) : exp(x/T) == exp2(x * SCALE_L2E)
#define SCALE_L2E 14.426950408889634f

#define NHP 8                       // K-blocks of 64 (each = two K=32 MFMA steps)
#define BM 128                      // tile edge
#define NT (N_ROWS / BM)            // 64 tile rows/cols
#define NPAIRS (NT * (NT + 1) / 2)  // 2080, divisible by 8

typedef __attribute__((ext_vector_type(4))) float f32x4;
typedef __attribute__((ext_vector_type(2))) long f8x16;  // 16 fp8 bytes = dwordx4

// ---------------- K1: normalize rows -> fp8 e4m3 Zn (hc-pair-interleaved), fp32 pos -------
// Zn layout: [hp=0..7][row=0..8191][64 B], where the 64 B for k-window [64hp,64hp+64) are
// arranged so byte slot lhi*16 holds k-octet (64hp + lhi*8 .. +8)   [even hc, lo 8B]
// and slot lhi*16+8 holds (64hp+32+lhi*8 .. +8)                     [odd hc, hi 8B].
// => one dwordx4 fragment load yields MFMA operands for BOTH K=32 steps of the hp.
__global__ __launch_bounds__(256) void k_normalize(const float* __restrict__ zi,
                                                   const float* __restrict__ zj,
                                                   unsigned char* __restrict__ Zn,
                                                   float* __restrict__ pos) {
    const int t = threadIdx.x;
    const int lane = t & 63;
    const int i = blockIdx.x * 4 + (t >> 6);
    const float* pa = zi + (size_t)i * D_DIM + lane * 8;
    const float* pb = zj + (size_t)i * D_DIM + lane * 8;
    const float4 a0 = *(const float4*)pa;
    const float4 a1 = *(const float4*)(pa + 4);
    const float4 b0 = *(const float4*)pb;
    const float4 b1 = *(const float4*)(pb + 4);
    float ssi = a0.x*a0.x + a0.y*a0.y + a0.z*a0.z + a0.w*a0.w
              + a1.x*a1.x + a1.y*a1.y + a1.z*a1.z + a1.w*a1.w;
    float ssj = b0.x*b0.x + b0.y*b0.y + b0.z*b0.z + b0.w*b0.w
              + b1.x*b1.x + b1.y*b1.y + b1.z*b1.z + b1.w*b1.w;
    float dt  = a0.x*b0.x + a0.y*b0.y + a0.z*b0.z + a0.w*b0.w
              + a1.x*b1.x + a1.y*b1.y + a1.z*b1.z + a1.w*b1.w;
    #pragma unroll
    for (int off = 1; off < 64; off <<= 1) {
        ssi += __shfl_xor(ssi, off);
        ssj += __shfl_xor(ssj, off);
        dt  += __shfl_xor(dt,  off);
    }
    const float si = 1.0f / fmaxf(sqrtf(ssi), 1e-12f);
    const float sj = 1.0f / fmaxf(sqrtf(ssj), 1e-12f);
    // pack 8 normalized values (k = lane*8 .. +8) -> 8 fp8 e4m3 (HW RNE)
    uint2 pi8, pj8;
    {
        int w0 = 0, w1 = 0;
        w0 = __builtin_amdgcn_cvt_pk_fp8_f32(a0.x * si, a0.y * si, w0, false);
        w0 = __builtin_amdgcn_cvt_pk_fp8_f32(a0.z * si, a0.w * si, w0, true);
        w1 = __builtin_amdgcn_cvt_pk_fp8_f32(a1.x * si, a1.y * si, w1, false);
        w1 = __builtin_amdgcn_cvt_pk_fp8_f32(a1.z * si, a1.w * si, w1, true);
        pi8.x = (unsigned)w0; pi8.y = (unsigned)w1;
        w0 = 0; w1 = 0;
        w0 = __builtin_amdgcn_cvt_pk_fp8_f32(b0.x * sj, b0.y * sj, w0, false);
        w0 = __builtin_amdgcn_cvt_pk_fp8_f32(b0.z * sj, b0.w * sj, w0, true);
        w1 = __builtin_amdgcn_cvt_pk_fp8_f32(b1.x * sj, b1.y * sj, w1, false);
        w1 = __builtin_amdgcn_cvt_pk_fp8_f32(b1.z * sj, b1.w * sj, w1, true);
        pj8.x = (unsigned)w0; pj8.y = (unsigned)w1;
    }
    // lane's k-octet o = lane&7 within hp = lane>>3; byte slot = (o&3)*16 + (o>>2)*8
    const size_t PLANE = (size_t)N_ROWS * 64;  // bytes per hp-plane
    const int o = lane & 7;
    const size_t off0 = (size_t)(lane >> 3) * PLANE + (o & 3) * 16 + (o >> 2) * 8;
    *(uint2*)(Zn + off0 + (size_t)i * 64) = pi8;
    *(uint2*)(Zn + off0 + (size_t)(B_ROWS + i) * 64) = pj8;
    if (lane == 0) pos[i] = 20.0f * dt * si * sj;  // positive logit counted twice: 2*dot/T
}

// ---------------- K2: symmetric fused S = Zn·Zn^T (fp8 MFMA) + per-row sum(exp(S/T)) ------
// NO LDS, NO BARRIERS. One 128x128 tile pair (I<=J) per block; 256 threads = 4 independent
// waves (2x2), wave tile 64x64 (acc = 64 VGPR -> 4 waves/SIMD). Fragments load directly
// global->VGPR as dwordx4 covering two K=32 steps each (8 loads per 64-K per wave).
// 4 MiB matrix is L2-resident. Latency hiding via TLP (4 waves/SIMD), not manual ILP.
__global__ __launch_bounds__(256, 4) void k_gemm_lse(const unsigned char* __restrict__ Zn,
                                                     float* __restrict__ rowsum_g) {
    const int t    = threadIdx.x;
    const int lane = t & 63;
    const int w    = t >> 6;
    const int wm   = w >> 1, wn = w & 1;          // 2 x 2 wave grid
    const int l15  = lane & 15, lhi = lane >> 4;

    // XCD-aware swizzle (bijective: NPAIRS % 8 == 0), then triangular (I,J) decode
    int bid = (blockIdx.x & 7) * (NPAIRS / 8) + (blockIdx.x >> 3);
    int I = 0;
    while (bid >= NT - I) { bid -= NT - I; ++I; }
    const int J = I + bid;
    const bool dg = (I == J);                // diagonal block: row-sums only, masked diag
    const int rowB = I * BM + wm * 64;       // wave's first output row
    const int colB = J * BM + wn * 64;       // wave's first output col

    const char* Zb = (const char*)Zn;
    const size_t PLANE = (size_t)N_ROWS * 64;  // bytes per hp-plane

    // fragment base pointers: lane (lhi,l15) reads row (base + l15 + 16*frag), slot lhi
    const char* pA = Zb + ((size_t)(rowB + l15)) * 64 + lhi * 16;
    const char* pB = Zb + ((size_t)(colB + l15)) * 64 + lhi * 16;

    f32x4 acc[4][4];
    #pragma unroll
    for (int a = 0; a < 4; ++a)
        #pragma unroll
        for (int b = 0; b < 4; ++b)
            #pragma unroll
            for (int q = 0; q < 4; ++q) acc[a][b][q] = 0.0f;

    for (int hp = 0; hp < NHP; ++hp) {
        f8x16 af[4], bg[4];
        const char* _a = pA + (size_t)hp * PLANE;
        const char* _b = pB + (size_t)hp * PLANE;
        #pragma unroll
        for (int mi = 0; mi < 4; ++mi) af[mi] = *(const f8x16*)(_a + mi * 1024);
        #pragma unroll
        for (int ni = 0; ni < 4; ++ni) bg[ni] = *(const f8x16*)(_b + ni * 1024);
        __builtin_amdgcn_s_setprio(1);
        #pragma unroll
        for (int mi = 0; mi < 4; ++mi)
            #pragma unroll
            for (int ni = 0; ni < 4; ++ni)
                acc[mi][ni] = __builtin_amdgcn_mfma_f32_16x16x32_fp8_fp8(
                    af[mi][0], bg[ni][0], acc[mi][ni], 0, 0, 0);
        #pragma unroll
        for (int mi = 0; mi < 4; ++mi)
            #pragma unroll
            for (int ni = 0; ni < 4; ++ni)
                acc[mi][ni] = __builtin_amdgcn_mfma_f32_16x16x32_fp8_fp8(
                    af[mi][1], bg[ni][1], acc[mi][ni], 0, 0, 0);
        __builtin_amdgcn_s_setprio(0);
    }

    // epilogue: e = exp2(S * 10*log2e); C/D layout: col=lane&15, row=(lane>>4)*4+reg
    float colsum[4] = {0.0f, 0.0f, 0.0f, 0.0f};
    #pragma unroll
    for (int mi = 0; mi < 4; ++mi) {
        const int growb = rowB + mi * 16 + lhi * 4;
        float rs[4] = {0.0f, 0.0f, 0.0f, 0.0f};
        if (dg) {
            #pragma unroll
            for (int ni = 0; ni < 4; ++ni) {
                const int gcol = colB + ni * 16 + l15;
                #pragma unroll
                for (int r = 0; r < 4; ++r) {
                    float arg = acc[mi][ni][r] * SCALE_L2E;
                    if (growb + r == gcol) arg = -1e30f;  // diagonal mask -> exp2 = 0
                    rs[r] += exp2f(arg);
                }
            }
        } else {
            #pragma unroll
            for (int ni = 0; ni < 4; ++ni)
                #pragma unroll
                for (int r = 0; r < 4; ++r) {
                    const float e = exp2f(acc[mi][ni][r] * SCALE_L2E);
                    rs[r] += e;
                    colsum[ni] += e;
                }
        }
        // row sums: reduce the 16 lanes sharing lhi; one atomic per (mi, r)
        #pragma unroll
        for (int r = 0; r < 4; ++r) {
            float v = rs[r];
            v += __shfl_xor(v, 1);
            v += __shfl_xor(v, 2);
            v += __shfl_xor(v, 4);
            v += __shfl_xor(v, 8);
            if (l15 == 0) atomicAdd(&rowsum_g[growb + r], v);
        }
    }
    if (!dg) {
        // column sums (symmetry): reduce across lhi groups; lanes lhi==0 hold col l15
        #pragma unroll
        for (int ni = 0; ni < 4; ++ni) {
            float c = colsum[ni];
            c += __shfl_xor(c, 16);
            c += __shfl_xor(c, 32);
            if (lhi == 0)
                atomicAdd(&rowsum_g[colB + ni * 16 + l15], c);
        }
    }
}

// ---------------- K3: loss = mean(ln(rowsum)) - mean(pos), single block ----------------
__global__ __launch_bounds__(1024) void k_finalize(const float* __restrict__ rowsum_g,
                                                   const float* __restrict__ pos,
                                                   float* __restrict__ out) {
    const int t = threadIdx.x;
    float l = 0.0f, p = 0.0f;
    #pragma unroll
    for (int q = 0; q < N_ROWS / 1024; ++q) l += logf(rowsum_g[t + q * 1024]);
    #pragma unroll
    for (int q = 0; q < B_ROWS / 1024; ++q) p += pos[t + q * 1024];
    #pragma unroll
    for (int off = 1; off < 64; off <<= 1) {
        l += __shfl_xor(l, off);
        p += __shfl_xor(p, off);
    }
    __shared__ float red[2][16];
    if ((t & 63) == 0) { red[0][t >> 6] = l; red[1][t >> 6] = p; }
    __syncthreads();
    if (t == 0) {
        float L = 0.0f, P = 0.0f;
        #pragma unroll
        for (int q = 0; q < 16; ++q) { L += red[0][q]; P += red[1][q]; }
        out[0] = (L - P) * (1.0f / (float)N_ROWS);
    }
}

extern "C" void kernel_launch(void* const* d_in, const int* in_sizes, int n_in,
                              void* d_out, int out_size, void* d_ws, size_t ws_size,
                              hipStream_t stream) {
    (void)in_sizes; (void)n_in; (void)out_size; (void)ws_size;
    const float* zi = (const float*)d_in[0];
    const float* zj = (const float*)d_in[1];

    // workspace layout
    const size_t ZN_BYTES = (size_t)N_ROWS * D_DIM;  // 4 MiB fp8 (hp-tiled)
    unsigned char* Zn     = (unsigned char*)d_ws;
    float* rowsum_g       = (float*)((char*)d_ws + ZN_BYTES);              // 8192 f32
    float* pos            = (float*)((char*)d_ws + ZN_BYTES + N_ROWS * 4); // 4096 f32

    // zero the atomically-accumulated rowsums
    hipMemsetAsync(rowsum_g, 0, N_ROWS * 4, stream);

    k_normalize<<<B_ROWS / 4, 256, 0, stream>>>(zi, zj, Zn, pos);
    k_gemm_lse<<<NPAIRS, 256, 0, stream>>>(Zn, rowsum_g);
    k_finalize<<<1, 1024, 0, stream>>>(rowsum_g, pos, (float*)d_out);
}

// Round 10
// 60.675 us; speedup vs baseline: 1.7634x; 1.2878x over previous
//
#include <hip/hip_runtime.h>
#include <stdint.h>

// Problem constants
#define D_DIM 512
#define B_ROWS 4096
#define N_ROWS 8192
// (1/TEMPERATURE) * log2(e) : exp(x/T) == exp2(x * SCALE_L2E)
#define SCALE_L2E 14.426950408889634f

#define NHP 8                       // K-blocks of 64 (each = two K=32 MFMA steps)
// 64-row tiles: 128 of them. Supers of 16 tiles (8 supers of 1024 rows).
// Super-pairs (SI<=SJ): 36. Sub-pairs: diag super = 136, off-diag = 256.
// Total blocks = 28*256 + 8*136 = 8256 = 8 * 1032 (bijective XCD swizzle).
#define NBLK 8256

typedef __attribute__((ext_vector_type(4))) float f32x4;
typedef __attribute__((ext_vector_type(2))) long f8x16;  // 16 fp8 bytes = dwordx4

// ---------------- K1: normalize rows -> fp8 e4m3 Zn (hp-interleaved), fp32 pos -------------
// Zn layout: [hp=0..7][row=0..8191][64 B]; byte slot lhi*16 holds k-octet (64hp+lhi*8..+8)
// and slot lhi*16+8 holds (64hp+32+lhi*8..+8) => one dwordx4 fragment load provides the
// MFMA A/B operands for BOTH K=32 steps of the hp.
__global__ __launch_bounds__(256) void k_normalize(const float* __restrict__ zi,
                                                   const float* __restrict__ zj,
                                                   unsigned char* __restrict__ Zn,
                                                   float* __restrict__ pos) {
    const int t = threadIdx.x;
    const int lane = t & 63;
    const int i = blockIdx.x * 4 + (t >> 6);
    const float* pa = zi + (size_t)i * D_DIM + lane * 8;
    const float* pb = zj + (size_t)i * D_DIM + lane * 8;
    const float4 a0 = *(const float4*)pa;
    const float4 a1 = *(const float4*)(pa + 4);
    const float4 b0 = *(const float4*)pb;
    const float4 b1 = *(const float4*)(pb + 4);
    float ssi = a0.x*a0.x + a0.y*a0.y + a0.z*a0.z + a0.w*a0.w
              + a1.x*a1.x + a1.y*a1.y + a1.z*a1.z + a1.w*a1.w;
    float ssj = b0.x*b0.x + b0.y*b0.y + b0.z*b0.z + b0.w*b0.w
              + b1.x*b1.x + b1.y*b1.y + b1.z*b1.z + b1.w*b1.w;
    float dt  = a0.x*b0.x + a0.y*b0.y + a0.z*b0.z + a0.w*b0.w
              + a1.x*b1.x + a1.y*b1.y + a1.z*b1.z + a1.w*b1.w;
    #pragma unroll
    for (int off = 1; off < 64; off <<= 1) {
        ssi += __shfl_xor(ssi, off);
        ssj += __shfl_xor(ssj, off);
        dt  += __shfl_xor(dt,  off);
    }
    const float si = 1.0f / fmaxf(sqrtf(ssi), 1e-12f);
    const float sj = 1.0f / fmaxf(sqrtf(ssj), 1e-12f);
    // pack 8 normalized values (k = lane*8 .. +8) -> 8 fp8 e4m3 (HW RNE)
    uint2 pi8, pj8;
    {
        int w0 = 0, w1 = 0;
        w0 = __builtin_amdgcn_cvt_pk_fp8_f32(a0.x * si, a0.y * si, w0, false);
        w0 = __builtin_amdgcn_cvt_pk_fp8_f32(a0.z * si, a0.w * si, w0, true);
        w1 = __builtin_amdgcn_cvt_pk_fp8_f32(a1.x * si, a1.y * si, w1, false);
        w1 = __builtin_amdgcn_cvt_pk_fp8_f32(a1.z * si, a1.w * si, w1, true);
        pi8.x = (unsigned)w0; pi8.y = (unsigned)w1;
        w0 = 0; w1 = 0;
        w0 = __builtin_amdgcn_cvt_pk_fp8_f32(b0.x * sj, b0.y * sj, w0, false);
        w0 = __builtin_amdgcn_cvt_pk_fp8_f32(b0.z * sj, b0.w * sj, w0, true);
        w1 = __builtin_amdgcn_cvt_pk_fp8_f32(b1.x * sj, b1.y * sj, w1, false);
        w1 = __builtin_amdgcn_cvt_pk_fp8_f32(b1.z * sj, b1.w * sj, w1, true);
        pj8.x = (unsigned)w0; pj8.y = (unsigned)w1;
    }
    // lane's k-octet o = lane&7 within hp = lane>>3; byte slot = (o&3)*16 + (o>>2)*8
    const size_t PLANE = (size_t)N_ROWS * 64;  // bytes per hp-plane
    const int o = lane & 7;
    const size_t off0 = (size_t)(lane >> 3) * PLANE + (o & 3) * 16 + (o >> 2) * 8;
    *(uint2*)(Zn + off0 + (size_t)i * 64) = pi8;
    *(uint2*)(Zn + off0 + (size_t)(B_ROWS + i) * 64) = pj8;
    if (lane == 0) pos[i] = 20.0f * dt * si * sj;  // positive logit counted twice: 2*dot/T
}

// ---------------- K2: symmetric fused S = Zn·Zn^T (fp8 MFMA) + per-row sum(exp(S/T)) ------
// ONE WAVE per block, 64x64 tile pair (I<=J over 64-row tiles). NO LDS, no barriers.
// Supertiled enumeration: super = 16 tiles (1 MiB working set per super-pair -> L2-hit
// reuse: each panel read by 16 concurrently-resident blocks). XCD swizzle gives each XCD
// a contiguous ~4.5-super-pair chunk. 4 waves/SIMD (VGPR<=128) hide ~200cy L2 latency
// under 154cy MFMA bursts.
__global__ __launch_bounds__(64, 4) void k_gemm_lse(const unsigned char* __restrict__ Zn,
                                                    float* __restrict__ rowsum_g) {
    const int lane = threadIdx.x & 63;
    const int l15  = lane & 15, lhi = lane >> 4;

    // XCD-aware swizzle (bijective: NBLK % 8 == 0)
    int g = (blockIdx.x & 7) * (NBLK / 8) + (blockIdx.x >> 3);
    // super-pair decode (SI<=SJ, sizes 136 diag / 256 off-diag)
    int SI = 0, SJ = 0;
    {
        bool found = false;
        for (SI = 0; SI < 8 && !found; ++SI) {
            for (SJ = SI; SJ < 8; ++SJ) {
                const int sz = (SI == SJ) ? 136 : 256;
                if (g < sz) { found = true; break; }
                g -= sz;
            }
        }
        --SI;  // loop increments past the found value
    }
    int di, dj;
    if (SI == SJ) {
        di = 0;
        while (g >= 16 - di) { g -= 16 - di; ++di; }
        dj = di + g;
    } else {
        di = g >> 4; dj = g & 15;
    }
    const int I = SI * 16 + di, J = SJ * 16 + dj;
    const bool dg = (I == J);
    const int rowB = I * 64;               // wave's first output row
    const int colB = J * 64;               // wave's first output col

    const char* Zb = (const char*)Zn;
    const size_t PLANE = (size_t)N_ROWS * 64;  // bytes per hp-plane

    // fragment base pointers: lane (lhi,l15) reads row (base + l15 + 16*frag), slot lhi
    const char* pA = Zb + ((size_t)(rowB + l15)) * 64 + lhi * 16;
    const char* pB = Zb + ((size_t)(colB + l15)) * 64 + lhi * 16;

    f32x4 acc[4][4];
    #pragma unroll
    for (int a = 0; a < 4; ++a)
        #pragma unroll
        for (int b = 0; b < 4; ++b)
            #pragma unroll
            for (int q = 0; q < 4; ++q) acc[a][b][q] = 0.0f;

    for (int hp = 0; hp < NHP; ++hp) {
        f8x16 af[4], bg[4];
        const char* _a = pA + (size_t)hp * PLANE;
        const char* _b = pB + (size_t)hp * PLANE;
        #pragma unroll
        for (int mi = 0; mi < 4; ++mi) af[mi] = *(const f8x16*)(_a + mi * 1024);
        #pragma unroll
        for (int ni = 0; ni < 4; ++ni) bg[ni] = *(const f8x16*)(_b + ni * 1024);
        __builtin_amdgcn_s_setprio(1);
        #pragma unroll
        for (int mi = 0; mi < 4; ++mi)
            #pragma unroll
            for (int ni = 0; ni < 4; ++ni)
                acc[mi][ni] = __builtin_amdgcn_mfma_f32_16x16x32_fp8_fp8(
                    af[mi][0], bg[ni][0], acc[mi][ni], 0, 0, 0);
        #pragma unroll
        for (int mi = 0; mi < 4; ++mi)
            #pragma unroll
            for (int ni = 0; ni < 4; ++ni)
                acc[mi][ni] = __builtin_amdgcn_mfma_f32_16x16x32_fp8_fp8(
                    af[mi][1], bg[ni][1], acc[mi][ni], 0, 0, 0);
        __builtin_amdgcn_s_setprio(0);
    }

    // epilogue: e = exp2(S * 10*log2e); C/D layout: col=lane&15, row=(lane>>4)*4+reg
    float colsum[4] = {0.0f, 0.0f, 0.0f, 0.0f};
    #pragma unroll
    for (int mi = 0; mi < 4; ++mi) {
        const int growb = rowB + mi * 16 + lhi * 4;
        float rs[4] = {0.0f, 0.0f, 0.0f, 0.0f};
        if (dg) {
            #pragma unroll
            for (int ni = 0; ni < 4; ++ni) {
                const int gcol = colB + ni * 16 + l15;
                #pragma unroll
                for (int r = 0; r < 4; ++r) {
                    float arg = acc[mi][ni][r] * SCALE_L2E;
                    if (growb + r == gcol) arg = -1e30f;  // diagonal mask -> exp2 = 0
                    rs[r] += exp2f(arg);
                }
            }
        } else {
            #pragma unroll
            for (int ni = 0; ni < 4; ++ni)
                #pragma unroll
                for (int r = 0; r < 4; ++r) {
                    const float e = exp2f(acc[mi][ni][r] * SCALE_L2E);
                    rs[r] += e;
                    colsum[ni] += e;
                }
        }
        // row sums: reduce the 16 lanes sharing lhi; one atomic per (mi, r)
        #pragma unroll
        for (int r = 0; r < 4; ++r) {
            float v = rs[r];
            v += __shfl_xor(v, 1);
            v += __shfl_xor(v, 2);
            v += __shfl_xor(v, 4);
            v += __shfl_xor(v, 8);
            if (l15 == 0) atomicAdd(&rowsum_g[growb + r], v);
        }
    }
    if (!dg) {
        // column sums (symmetry): reduce across lhi groups; lanes lhi==0 hold col l15
        #pragma unroll
        for (int ni = 0; ni < 4; ++ni) {
            float c = colsum[ni];
            c += __shfl_xor(c, 16);
            c += __shfl_xor(c, 32);
            if (lhi == 0)
                atomicAdd(&rowsum_g[colB + ni * 16 + l15], c);
        }
    }
}

// ---------------- K3: loss = mean(ln(rowsum)) - mean(pos), single block ----------------
__global__ __launch_bounds__(1024) void k_finalize(const float* __restrict__ rowsum_g,
                                                   const float* __restrict__ pos,
                                                   float* __restrict__ out) {
    const int t = threadIdx.x;
    float l = 0.0f, p = 0.0f;
    #pragma unroll
    for (int q = 0; q < N_ROWS / 1024; ++q) l += logf(rowsum_g[t + q * 1024]);
    #pragma unroll
    for (int q = 0; q < B_ROWS / 1024; ++q) p += pos[t + q * 1024];
    #pragma unroll
    for (int off = 1; off < 64; off <<= 1) {
        l += __shfl_xor(l, off);
        p += __shfl_xor(p, off);
    }
    __shared__ float red[2][16];
    if ((t & 63) == 0) { red[0][t >> 6] = l; red[1][t >> 6] = p; }
    __syncthreads();
    if (t == 0) {
        float L = 0.0f, P = 0.0f;
        #pragma unroll
        for (int q = 0; q < 16; ++q) { L += red[0][q]; P += red[1][q]; }
        out[0] = (L - P) * (1.0f / (float)N_ROWS);
    }
}

extern "C" void kernel_launch(void* const* d_in, const int* in_sizes, int n_in,
                              void* d_out, int out_size, void* d_ws, size_t ws_size,
                              hipStream_t stream) {
    (void)in_sizes; (void)n_in; (void)out_size; (void)ws_size;
    const float* zi = (const float*)d_in[0];
    const float* zj = (const float*)d_in[1];

    // workspace layout
    const size_t ZN_BYTES = (size_t)N_ROWS * D_DIM;  // 4 MiB fp8 (hp-tiled)
    unsigned char* Zn     = (unsigned char*)d_ws;
    float* rowsum_g       = (float*)((char*)d_ws + ZN_BYTES);              // 8192 f32
    float* pos            = (float*)((char*)d_ws + ZN_BYTES + N_ROWS * 4); // 4096 f32

    // zero the atomically-accumulated rowsums
    hipMemsetAsync(rowsum_g, 0, N_ROWS * 4, stream);

    k_normalize<<<B_ROWS / 4, 256, 0, stream>>>(zi, zj, Zn, pos);
    k_gemm_lse<<<NBLK, 64, 0, stream>>>(Zn, rowsum_g);
    k_finalize<<<1, 1024, 0, stream>>>(rowsum_g, pos, (float*)d_out);
}